// Round 12
// baseline (16692.140 us; speedup 1.0000x reference)
//
#include <hip/hip_runtime.h>
#include <math.h>

#define NROWS 16384
#define KC    1024
#define NBLK  256
#define NTHR  1024
#define WPB   16      // waves per block
#define RPW   4       // rows per wave; 64 rows per block
#define CPB   4       // regular columns owned per block (block 255 also owns col 1024)
#define VSTR  1056    // padded stride for varr
#define ZSTR  1088    // u64 stride for tagged zpart rows
#define BSTR  1088    // u64 stride for tagged-b replicas
#define NITER 1000

// relaxed agent-scope (device-coherent) access
#define AL(p)    __hip_atomic_load((p), __ATOMIC_RELAXED, __HIP_MEMORY_SCOPE_AGENT)
#define AS(p,v)  __hip_atomic_store((p), (v), __ATOMIC_RELAXED, __HIP_MEMORY_SCOPE_AGENT)

__device__ __forceinline__ float wave_sum(float v) {
#pragma unroll
  for (int o = 32; o > 0; o >>= 1) v += __shfl_xor(v, o, 64);
  return v;
}
__device__ __forceinline__ float wave_max(float v) {
#pragma unroll
  for (int o = 32; o > 0; o >>= 1) v = fmaxf(v, __shfl_xor(v, o, 64));
  return v;
}

// bf16 pack/unpack (RNE)
__device__ __forceinline__ unsigned short f2b(float f) {
  unsigned u = __float_as_uint(f);
  u += 0x7FFFu + ((u >> 16) & 1u);
  return (unsigned short)(u >> 16);
}
__device__ __forceinline__ float b2f(unsigned h) {
  return __uint_as_float(h << 16);
}
__device__ __forceinline__ void unpack8(const uint4 p, float* f) {
  f[0] = b2f(p.x & 0xffffu); f[1] = b2f(p.x >> 16);
  f[2] = b2f(p.y & 0xffffu); f[3] = b2f(p.y >> 16);
  f[4] = b2f(p.z & 0xffffu); f[5] = b2f(p.z >> 16);
  f[6] = b2f(p.w & 0xffffu); f[7] = b2f(p.w >> 16);
}
__device__ __forceinline__ uint4 pack8(const float* f) {
  uint4 p;
  p.x = (unsigned)f2b(f[0]) | ((unsigned)f2b(f[1]) << 16);
  p.y = (unsigned)f2b(f[2]) | ((unsigned)f2b(f[3]) << 16);
  p.z = (unsigned)f2b(f[4]) | ((unsigned)f2b(f[5]) << 16);
  p.w = (unsigned)f2b(f[6]) | ((unsigned)f2b(f[7]) << 16);
  return p;
}

#define TAGOF(v)  ((unsigned)((v) >> 32))
#define PAYOF(v)  (__uint_as_float((unsigned)((v) & 0xffffffffull)))
#define MKTAG(s,f) (((unsigned long long)(s) << 32) | (unsigned long long)__float_as_uint(f))

// ws layout (memset [0, 2314240) each launch, captured in the graph):
//   float varr[2*VSTR]      @ 4096     dual potentials (ping-pong)
//   u64   zp64[NBLK][ZSTR]  @ 16384    tagged z partials; [KC]=zl, [KC+1]=block amax
//   u64   brep64[8][BSTR]   @ 2244608  tagged b replicas; [KC]=b_last, [KC+1]=global amax
// All cross-block values are tag-carried (hi=seq, equality-polled); no barriers.

// Lane-column mapping: lane l owns cols [8l, 8l+8) and [512+8l, 512+8l+8).
// zred row layout (1024 floats): chunk k (0..3) at [k*256 + lane*4 .. +3].
__global__ __launch_bounds__(NTHR, 4)
void sk_coop(const float* __restrict__ X, float* __restrict__ Qf, void* __restrict__ wsv)
{
  const int g    = blockIdx.x;
  const int tid  = threadIdx.x;
  const int wv   = tid >> 6;
  const int lane = tid & 63;
  const int row0 = (g * WPB + wv) * RPW;   // global row base for this wave

  float* varr = (float*)((char*)wsv + 4096);                          // [2*VSTR]
  unsigned long long* zp64   = (unsigned long long*)((char*)wsv + 16384);
  unsigned long long* brep64 = (unsigned long long*)((char*)wsv + 2244608);
  unsigned long long* myrep  = brep64 + (size_t)(((unsigned)g) & 7u) * BSTR;

  // ---- LDS: whole Q tile resident across the loop (131 KB) ----
  __shared__ unsigned short Qs[64 * KC];      // bf16, row lr at Qs + lr*KC
  __shared__ float zred[4 * KC];              // 16 KB z accumulate (4 rows)
  __shared__ float bstage[VSTR];              // persists across iterations
  __shared__ float rq[64], rxm[64], rlr[64], ra[64], ru[64];  // per-local-row state
  __shared__ float wlds[CPB];
  __shared__ float ldss[64];   // 0..31 z-reduce / bmax, 32..55 P2, 62 gamax

  const float FI   = (float)(1.0 / 1.1);
  const float FIM1 = (float)(1.0 / 1.1 - 1.0);
  const float TINY = 1.1920928955078125e-07f;
  const float PA   = 1.0f / 16384.0f;
  const float PBJ  = 0.5f / 1024.0f;
  const float PBL  = 0.5f;
  const float EPSF = 0.1f;

  // ---------------- init: softmax stats + Q0 (bf16) into LDS ----------------
  if (tid < CPB) {
    AS(&varr[g * CPB + tid], 0.0f);
    AS(&varr[VSTR + g * CPB + tid], 0.0f);
    wlds[tid] = 1.0f;
  }
  if (g == NBLK - 1 && tid == CPB) { AS(&varr[KC], 0.0f); AS(&varr[VSTR + KC], 0.0f); }
  bstage[tid] = 1.0f / 1025.0f;
  if (tid == 0) bstage[KC] = 1.0f / 1025.0f;
#pragma unroll
  for (int r = 0; r < RPW; ++r) {
    const int i  = row0 + r;
    const int lr = wv * RPW + r;
    const float* xr = X + (size_t)i * KC;
    float x[16];
    {
      const float4 t0 = *reinterpret_cast<const float4*>(xr + 8 * lane);
      const float4 t1 = *reinterpret_cast<const float4*>(xr + 8 * lane + 4);
      const float4 t2 = *reinterpret_cast<const float4*>(xr + 512 + 8 * lane);
      const float4 t3 = *reinterpret_cast<const float4*>(xr + 512 + 8 * lane + 4);
      x[0]=t0.x; x[1]=t0.y; x[2]=t0.z; x[3]=t0.w;
      x[4]=t1.x; x[5]=t1.y; x[6]=t1.z; x[7]=t1.w;
      x[8]=t2.x; x[9]=t2.y; x[10]=t2.z; x[11]=t2.w;
      x[12]=t3.x; x[13]=t3.y; x[14]=t3.z; x[15]=t3.w;
    }
    float mx = -INFINITY;
#pragma unroll
    for (int e = 0; e < 16; ++e) mx = fmaxf(mx, x[e]);
    mx = wave_max(mx);
    float s = 0.0f;
#pragma unroll
    for (int e = 0; e < 16; ++e) s += expf(x[e] - mx);
    s = wave_sum(s);
    const float L = logf(s);
    if (lane == 0) { rxm[lr] = mx; rlr[lr] = L; ru[lr] = 0.0f; rq[lr] = 1.0f; }
    float q[16];
#pragma unroll
    for (int e = 0; e < 16; ++e) q[e] = expf(((x[e] - mx) - L) / EPSF);
    uint4* qrow = (uint4*)(Qs + (size_t)lr * KC);
    qrow[lane]      = pack8(q);
    qrow[64 + lane] = pack8(q + 8);
  }
  __syncthreads();   // bstage + Qs ready (block-local; no global sync needed)

  // ---------------- main loop ----------------
  int vp = 0, stab = 0;
  unsigned seq = 0;

  for (int it = 0; it < NITER; ++it) {
    float zac[16];
#pragma unroll
    for (int e = 0; e < 16; ++e) zac[e] = 0.0f;
    float zl = 0.0f, amx = -INFINITY;

    float bf[16];
    {
      const float4 t0 = *reinterpret_cast<const float4*>(&bstage[8 * lane]);
      const float4 t1 = *reinterpret_cast<const float4*>(&bstage[8 * lane + 4]);
      const float4 t2 = *reinterpret_cast<const float4*>(&bstage[512 + 8 * lane]);
      const float4 t3 = *reinterpret_cast<const float4*>(&bstage[512 + 8 * lane + 4]);
      bf[0]=t0.x; bf[1]=t0.y; bf[2]=t0.z; bf[3]=t0.w;
      bf[4]=t1.x; bf[5]=t1.y; bf[6]=t1.z; bf[7]=t1.w;
      bf[8]=t2.x; bf[9]=t2.y; bf[10]=t2.z; bf[11]=t2.w;
      bf[12]=t3.x; bf[13]=t3.y; bf[14]=t3.z; bf[15]=t3.w;
    }
    const float bl = bstage[KC];

    if (!stab) {
      // ---- P1 from LDS: y = Q b ; a = Pa/y ; z += a_i * Q_i ----
#pragma unroll
      for (int r = 0; r < RPW; ++r) {
        const int lr = wv * RPW + r;
        const uint4* qrow = (const uint4*)(Qs + (size_t)lr * KC);
        const uint4 p0 = qrow[lane], p1 = qrow[64 + lane];
        float q[16];
        unpack8(p0, q); unpack8(p1, q + 8);
        float d = 0.0f;
#pragma unroll
        for (int e = 0; e < 16; ++e) d = fmaf(q[e], bf[e], d);
        const float ql = rq[lr];
        const float y  = wave_sum(d) + ql * bl;
        const float ai = PA / y;
        if (lane == 0) ra[lr] = ai;
        amx = fmaxf(amx, ai);
#pragma unroll
        for (int e = 0; e < 16; ++e) zac[e] = fmaf(ai, q[e], zac[e]);
        zl = fmaf(ai, ql, zl);
      }
    } else {
      // ---- P1 deferred stabilization: rewrite Q (LDS) from logits; b := ones ----
      if (tid < CPB) {
        const int j = g * CPB + tid;
        const float bj = bstage[j];
        AS(&varr[(vp ^ 1) * VSTR + j], AL(&varr[vp * VSTR + j]) + EPSF * logf(bj + TINY));
        wlds[tid] = wlds[tid] * powf(bj, FIM1);
      }
      if (g == NBLK - 1 && tid == CPB)
        AS(&varr[(vp ^ 1) * VSTR + KC], AL(&varr[vp * VSTR + KC]) + EPSF * logf(bstage[KC] + TINY));
      float v2f[16];
#pragma unroll
      for (int e = 0; e < 16; ++e) {
        const int j = (e < 8) ? (8 * lane + e) : (512 + 8 * lane + (e - 8));
        v2f[e] = AL(&varr[vp * VSTR + j]) + EPSF * logf(bstage[j] + TINY);
      }
      const float v2l = AL(&varr[vp * VSTR + KC]) + EPSF * logf(bstage[KC] + TINY);
#pragma unroll
      for (int r = 0; r < RPW; ++r) {
        const int i  = row0 + r;
        const int lr = wv * RPW + r;
        const float u2 = ru[lr] + EPSF * logf(ra[lr]);
        if (lane == 0) ru[lr] = u2;
        const float mi = rxm[lr], Li = rlr[lr];
        const float* xr = X + (size_t)i * KC;
        float q[16];
        {
          const float4 t0 = *reinterpret_cast<const float4*>(xr + 8 * lane);
          const float4 t1 = *reinterpret_cast<const float4*>(xr + 8 * lane + 4);
          const float4 t2 = *reinterpret_cast<const float4*>(xr + 512 + 8 * lane);
          const float4 t3 = *reinterpret_cast<const float4*>(xr + 512 + 8 * lane + 4);
          q[0]=t0.x; q[1]=t0.y; q[2]=t0.z; q[3]=t0.w;
          q[4]=t1.x; q[5]=t1.y; q[6]=t1.z; q[7]=t1.w;
          q[8]=t2.x; q[9]=t2.y; q[10]=t2.z; q[11]=t2.w;
          q[12]=t3.x; q[13]=t3.y; q[14]=t3.z; q[15]=t3.w;
        }
#pragma unroll
        for (int e = 0; e < 16; ++e) {
          const float cost = Li - (q[e] - mi);
          q[e] = expf((u2 - cost + v2f[e]) / EPSF);
        }
        uint4* qrow = (uint4*)(Qs + (size_t)lr * KC);
        qrow[lane]      = pack8(q);
        qrow[64 + lane] = pack8(q + 8);
        float d = 0.0f;
#pragma unroll
        for (int e = 0; e < 16; ++e) d += q[e];
        const float ql = expf((u2 + v2l) / EPSF);
        if (lane == 0) rq[lr] = ql;
        const float y  = wave_sum(d) + ql;
        const float ai = PA / y;
        if (lane == 0) ra[lr] = ai;
        amx = fmaxf(amx, ai);
#pragma unroll
        for (int e = 0; e < 16; ++e) zac[e] = fmaf(ai, q[e], zac[e]);
        zl = fmaf(ai, ql, zl);
      }
      vp ^= 1;
    }

    // ---- z reduce: 4-phase accumulate into zred[4][KC] (conflict-free layout) ----
    const float wamx = wave_max(amx);
    if (lane == 0) { ldss[wv] = zl; ldss[16 + wv] = wamx; }
    float* zrow = zred + (wv & 3) * KC;
    const int gp = wv >> 2;
    __syncthreads();
    if (gp == 0) {
      *reinterpret_cast<float4*>(&zrow[lane * 4])       = make_float4(zac[0], zac[1], zac[2], zac[3]);
      *reinterpret_cast<float4*>(&zrow[256 + lane * 4]) = make_float4(zac[4], zac[5], zac[6], zac[7]);
      *reinterpret_cast<float4*>(&zrow[512 + lane * 4]) = make_float4(zac[8], zac[9], zac[10], zac[11]);
      *reinterpret_cast<float4*>(&zrow[768 + lane * 4]) = make_float4(zac[12], zac[13], zac[14], zac[15]);
    }
    __syncthreads();
#pragma unroll
    for (int p = 1; p < 4; ++p) {
      if (gp == p) {
        float4 t;
        t = *reinterpret_cast<float4*>(&zrow[lane * 4]);
        t.x += zac[0]; t.y += zac[1]; t.z += zac[2]; t.w += zac[3];
        *reinterpret_cast<float4*>(&zrow[lane * 4]) = t;
        t = *reinterpret_cast<float4*>(&zrow[256 + lane * 4]);
        t.x += zac[4]; t.y += zac[5]; t.z += zac[6]; t.w += zac[7];
        *reinterpret_cast<float4*>(&zrow[256 + lane * 4]) = t;
        t = *reinterpret_cast<float4*>(&zrow[512 + lane * 4]);
        t.x += zac[8]; t.y += zac[9]; t.z += zac[10]; t.w += zac[11];
        *reinterpret_cast<float4*>(&zrow[512 + lane * 4]) = t;
        t = *reinterpret_cast<float4*>(&zrow[768 + lane * 4]);
        t.x += zac[12]; t.y += zac[13]; t.z += zac[14]; t.w += zac[15];
        *reinterpret_cast<float4*>(&zrow[768 + lane * 4]) = t;
      }
      __syncthreads();
    }
    ++seq;
    {
      const int wi   = tid & 511;
      const int fidx = ((tid >> 9) * 2 + ((wi & 7) >> 2)) * 256 + (wi >> 3) * 4 + (wi & 3);
      const float s = ((zred[fidx] + zred[KC + fidx]) + zred[2 * KC + fidx]) + zred[3 * KC + fidx];
      AS(&zp64[(size_t)g * ZSTR + tid], MKTAG(seq, s));
    }
    if (tid == 0) {
      float zt = 0.0f;
#pragma unroll
      for (int w = 0; w < 16; ++w) zt += ldss[w];
      AS(&zp64[(size_t)g * ZSTR + KC], MKTAG(seq, zt));
      float am = ldss[16];
#pragma unroll
      for (int w = 1; w < 16; ++w) am = fmaxf(am, ldss[16 + w]);
      AS(&zp64[(size_t)g * ZSTR + KC + 1], MKTAG(seq, am));
    }

    // ---- P2 (owner): poll tagged column slice, reduce, publish tagged b ----
    if (tid < 256) {
      const unsigned long long* zb = zp64 + (size_t)tid * ZSTR + g * CPB;
      unsigned long long v0, v1, v2, v3;
      for (;;) {
        v0 = AL(zb + 0); v1 = AL(zb + 1); v2 = AL(zb + 2); v3 = AL(zb + 3);
        if (TAGOF(v0) == seq && TAGOF(v1) == seq && TAGOF(v2) == seq && TAGOF(v3) == seq) break;
        __builtin_amdgcn_s_sleep(2);
      }
      const float s0 = wave_sum(PAYOF(v0));
      const float s1 = wave_sum(PAYOF(v1));
      const float s2 = wave_sum(PAYOF(v2));
      const float s3 = wave_sum(PAYOF(v3));
      float sl = 0.0f, sa = -INFINITY;
      if (g == NBLK - 1) {
        unsigned long long vk, va;
        for (;;) {
          vk = AL(&zp64[(size_t)tid * ZSTR + KC]);
          va = AL(&zp64[(size_t)tid * ZSTR + KC + 1]);
          if (TAGOF(vk) == seq && TAGOF(va) == seq) break;
          __builtin_amdgcn_s_sleep(2);
        }
        sl = wave_sum(PAYOF(vk));
        sa = wave_max(PAYOF(va));
      }
      if (lane == 0) {
        ldss[32 + wv * 4 + 0] = s0; ldss[32 + wv * 4 + 1] = s1;
        ldss[32 + wv * 4 + 2] = s2; ldss[32 + wv * 4 + 3] = s3;
        ldss[48 + wv] = sl; ldss[52 + wv] = sa;
      }
    }
    __syncthreads();
    if (tid == 0) {
#pragma unroll
      for (int c = 0; c < CPB; ++c) {
        const float z    = ((ldss[32 + c] + ldss[36 + c]) + ldss[40 + c]) + ldss[44 + c];
        const float bnew = powf(PBJ / z, FI) * wlds[c];
        const unsigned long long tv = MKTAG(seq, bnew);
#pragma unroll
        for (int rep = 0; rep < 8; ++rep) AS(&brep64[(size_t)rep * BSTR + g * CPB + c], tv);
      }
      if (g == NBLK - 1) {
        const float zk = ((ldss[48] + ldss[49]) + ldss[50]) + ldss[51];
        const float bn = PBL / zk;
        const float ga = fmaxf(fmaxf(ldss[52], ldss[53]), fmaxf(ldss[54], ldss[55]));
        const unsigned long long tvb = MKTAG(seq, bn);
        const unsigned long long tva = MKTAG(seq, ga);
#pragma unroll
        for (int rep = 0; rep < 8; ++rep) {
          AS(&brep64[(size_t)rep * BSTR + KC], tvb);
          AS(&brep64[(size_t)rep * BSTR + KC + 1], tva);
        }
      }
    }

    // ---- consume: poll tagged b replica, stage to LDS, stab decision ----
    {
      unsigned long long v;
      for (;;) {
        v = AL(&myrep[tid]);
        if (TAGOF(v) == seq) break;
        __builtin_amdgcn_s_sleep(4);
      }
      const float bv = PAYOF(v);
      bstage[tid] = bv;
      if (tid == 0) {
        for (;;) {
          v = AL(&myrep[KC]);
          if (TAGOF(v) == seq) break;
          __builtin_amdgcn_s_sleep(4);
        }
        bstage[KC] = PAYOF(v);
      }
      if (tid == 1) {
        for (;;) {
          v = AL(&myrep[KC + 1]);
          if (TAGOF(v) == seq) break;
          __builtin_amdgcn_s_sleep(4);
        }
        ldss[62] = PAYOF(v);
      }
      const float wm = wave_max(bv);
      if (lane == 0) ldss[wv] = wm;
      __syncthreads();   // bstage + ldss[0..15] + ldss[62] ready
      float bmx = ldss[0];
#pragma unroll
      for (int w = 1; w < 16; ++w) bmx = fmaxf(bmx, ldss[w]);
      bmx = fmaxf(bmx, bstage[KC]);
      stab = (fmaxf(ldss[62], bmx) > 1e8f) ? 1 : 0;
    }
  }

  // ---------------- epilogue (bstage/stab from final iteration) ----------------
  if (!stab) {
    // plan = n * a_i * Qs_ij * b_j   (Q from LDS; single pass)
    float bf[16];
    {
      const float4 t0 = *reinterpret_cast<const float4*>(&bstage[8 * lane]);
      const float4 t1 = *reinterpret_cast<const float4*>(&bstage[8 * lane + 4]);
      const float4 t2 = *reinterpret_cast<const float4*>(&bstage[512 + 8 * lane]);
      const float4 t3 = *reinterpret_cast<const float4*>(&bstage[512 + 8 * lane + 4]);
      bf[0]=t0.x; bf[1]=t0.y; bf[2]=t0.z; bf[3]=t0.w;
      bf[4]=t1.x; bf[5]=t1.y; bf[6]=t1.z; bf[7]=t1.w;
      bf[8]=t2.x; bf[9]=t2.y; bf[10]=t2.z; bf[11]=t2.w;
      bf[12]=t3.x; bf[13]=t3.y; bf[14]=t3.z; bf[15]=t3.w;
    }
#pragma unroll
    for (int r = 0; r < RPW; ++r) {
      const int i  = row0 + r;
      const int lr = wv * RPW + r;
      const float an = ra[lr] * 16384.0f;
      const uint4* qrow = (const uint4*)(Qs + (size_t)lr * KC);
      const uint4 p0 = qrow[lane], p1 = qrow[64 + lane];
      float q[16];
      unpack8(p0, q); unpack8(p1, q + 8);
      float* orow = Qf + (size_t)i * KC;
      *reinterpret_cast<float4*>(orow + 8 * lane) =
        make_float4(an*q[0]*bf[0], an*q[1]*bf[1], an*q[2]*bf[2], an*q[3]*bf[3]);
      *reinterpret_cast<float4*>(orow + 8 * lane + 4) =
        make_float4(an*q[4]*bf[4], an*q[5]*bf[5], an*q[6]*bf[6], an*q[7]*bf[7]);
      *reinterpret_cast<float4*>(orow + 512 + 8 * lane) =
        make_float4(an*q[8]*bf[8], an*q[9]*bf[9], an*q[10]*bf[10], an*q[11]*bf[11]);
      *reinterpret_cast<float4*>(orow + 512 + 8 * lane + 4) =
        make_float4(an*q[12]*bf[12], an*q[13]*bf[13], an*q[14]*bf[14], an*q[15]*bf[15]);
    }
  } else {
    // pending stabilization at exit: plan = n * exp((u2 - cost + v2^T)/eps), from X
    float v2f[16];
#pragma unroll
    for (int e = 0; e < 16; ++e) {
      const int j = (e < 8) ? (8 * lane + e) : (512 + 8 * lane + (e - 8));
      v2f[e] = AL(&varr[vp * VSTR + j]) + EPSF * logf(bstage[j] + TINY);
    }
#pragma unroll
    for (int r = 0; r < RPW; ++r) {
      const int i  = row0 + r;
      const int lr = wv * RPW + r;
      const float u2 = ru[lr] + EPSF * logf(ra[lr]);
      const float mi = rxm[lr], Li = rlr[lr];
      const float* xr = X + (size_t)i * KC;
      float x[16];
      {
        const float4 t0 = *reinterpret_cast<const float4*>(xr + 8 * lane);
        const float4 t1 = *reinterpret_cast<const float4*>(xr + 8 * lane + 4);
        const float4 t2 = *reinterpret_cast<const float4*>(xr + 512 + 8 * lane);
        const float4 t3 = *reinterpret_cast<const float4*>(xr + 512 + 8 * lane + 4);
        x[0]=t0.x; x[1]=t0.y; x[2]=t0.z; x[3]=t0.w;
        x[4]=t1.x; x[5]=t1.y; x[6]=t1.z; x[7]=t1.w;
        x[8]=t2.x; x[9]=t2.y; x[10]=t2.z; x[11]=t2.w;
        x[12]=t3.x; x[13]=t3.y; x[14]=t3.z; x[15]=t3.w;
      }
      float q[16];
#pragma unroll
      for (int e = 0; e < 16; ++e)
        q[e] = expf((u2 - (Li - (x[e] - mi)) + v2f[e]) / EPSF) * 16384.0f;
      float* orow = Qf + (size_t)i * KC;
      *reinterpret_cast<float4*>(orow + 8 * lane)           = make_float4(q[0], q[1], q[2], q[3]);
      *reinterpret_cast<float4*>(orow + 8 * lane + 4)       = make_float4(q[4], q[5], q[6], q[7]);
      *reinterpret_cast<float4*>(orow + 512 + 8 * lane)     = make_float4(q[8], q[9], q[10], q[11]);
      *reinterpret_cast<float4*>(orow + 512 + 8 * lane + 4) = make_float4(q[12], q[13], q[14], q[15]);
    }
  }
}

extern "C" void kernel_launch(void* const* d_in, const int* in_sizes, int n_in,
                              void* d_out, int out_size, void* d_ws, size_t ws_size,
                              hipStream_t stream)
{
  (void)in_sizes; (void)n_in; (void)out_size; (void)ws_size;
  const float* X = (const float*)d_in[0];
  float* Qf = (float*)d_out;
  // clear varr + all tag regions (zp64 + brep64); captured in the graph so
  // every replay starts with tag=0 (never equals any seq in [1,1000])
  hipMemsetAsync(d_ws, 0, 2314240, stream);
  void* args[3] = { (void*)&X, (void*)&Qf, (void*)&d_ws };
  hipLaunchCooperativeKernel((const void*)sk_coop, dim3(NBLK), dim3(NTHR),
                             args, 0, stream);
}

// Round 13
// 13360.851 us; speedup vs baseline: 1.2493x; 1.2493x over previous
//
#include <hip/hip_runtime.h>
#include <math.h>

#define NROWS 16384
#define KC    1024
#define NBLK  256
#define NTHR  1024
#define WPB   16      // waves per block
#define RPW   4       // rows per wave; 64 rows per block
#define CPB   4       // regular columns owned per block (block 255 also owns col 1024)
#define VSTR  1056    // padded stride for varr / zpart
#define BSTR  1088    // u64 stride for tagged-b replicas
#define NITER 1000

// relaxed agent-scope (device-coherent) access
#define AL(p)    __hip_atomic_load((p), __ATOMIC_RELAXED, __HIP_MEMORY_SCOPE_AGENT)
#define AS(p,v)  __hip_atomic_store((p), (v), __ATOMIC_RELAXED, __HIP_MEMORY_SCOPE_AGENT)

__device__ __forceinline__ float wave_sum(float v) {
#pragma unroll
  for (int o = 32; o > 0; o >>= 1) v += __shfl_xor(v, o, 64);
  return v;
}
__device__ __forceinline__ float wave_max(float v) {
#pragma unroll
  for (int o = 32; o > 0; o >>= 1) v = fmaxf(v, __shfl_xor(v, o, 64));
  return v;
}

// bf16 pack/unpack (RNE)
__device__ __forceinline__ unsigned short f2b(float f) {
  unsigned u = __float_as_uint(f);
  u += 0x7FFFu + ((u >> 16) & 1u);
  return (unsigned short)(u >> 16);
}
__device__ __forceinline__ float b2f(unsigned h) {
  return __uint_as_float(h << 16);
}
__device__ __forceinline__ void unpack8(const uint4 p, float* f) {
  f[0] = b2f(p.x & 0xffffu); f[1] = b2f(p.x >> 16);
  f[2] = b2f(p.y & 0xffffu); f[3] = b2f(p.y >> 16);
  f[4] = b2f(p.z & 0xffffu); f[5] = b2f(p.z >> 16);
  f[6] = b2f(p.w & 0xffffu); f[7] = b2f(p.w >> 16);
}
__device__ __forceinline__ uint4 pack8(const float* f) {
  uint4 p;
  p.x = (unsigned)f2b(f[0]) | ((unsigned)f2b(f[1]) << 16);
  p.y = (unsigned)f2b(f[2]) | ((unsigned)f2b(f[3]) << 16);
  p.z = (unsigned)f2b(f[4]) | ((unsigned)f2b(f[5]) << 16);
  p.w = (unsigned)f2b(f[6]) | ((unsigned)f2b(f[7]) << 16);
  return p;
}

#define TAGOF(v)  ((unsigned)((v) >> 32))
#define PAYOF(v)  (__uint_as_float((unsigned)((v) & 0xffffffffull)))
#define MKTAG(s,f) (((unsigned long long)(s) << 32) | (unsigned long long)__float_as_uint(f))

// ws layout:
//   u64 arr[256]     @ 0      arrival: hi=seq, lo=float(block amax)   [memset 0]
//   u64 rel64[256*4] @ 2048   per-block release (32B apart): hi=seq, lo=float(gamax) [memset 0]
//   floats           @ 16384  varr[2*VSTR], zpart[NBLK][VSTR]
//   u64 brep64[8][BSTR] after zpart: tagged b, hi=seq (equality-polled), lo=f32 bits

// Lane-column mapping: lane l owns cols [8l, 8l+8) and [512+8l, 512+8l+8).
// zred row layout (1024 floats): chunk k (0..3) at [k*256 + lane*4 .. +3].
__global__ __launch_bounds__(NTHR, 4)
void sk_coop(const float* __restrict__ X, float* __restrict__ Qf, void* __restrict__ wsv)
{
  const int g    = blockIdx.x;
  const int tid  = threadIdx.x;
  const int wv   = tid >> 6;
  const int lane = tid & 63;
  const int row0 = (g * WPB + wv) * RPW;   // global row base for this wave

  unsigned long long* arr   = (unsigned long long*)wsv;                  // [256]
  unsigned long long* rel64 = (unsigned long long*)((char*)wsv + 2048);  // [256*4]
  float* varr  = (float*)((char*)wsv + 16384);                           // [2*VSTR]
  float* zpart = varr + 2 * VSTR;                                        // [NBLK][VSTR]
  unsigned long long* brep64 = (unsigned long long*)(zpart + (size_t)NBLK * VSTR);
  unsigned long long* myrep  = brep64 + (size_t)(((unsigned)g) & 7u) * BSTR;

  // ---- LDS: whole Q tile resident across the loop (131 KB) ----
  __shared__ unsigned short Qs[64 * KC];      // bf16, row lr at Qs + lr*KC
  __shared__ float zred[4 * KC];              // 16 KB z accumulate (4 rows)
  __shared__ float bstage[VSTR];              // persists across iterations
  __shared__ float rq[64], rxm[64], rlr[64], ra[64], ru[64];  // per-local-row state
  __shared__ float wlds[CPB];
  __shared__ float ldss[64];   // 0..31 z-reduce/bmax, 32..55 P2, 56..59 sweep, 61 blkamax, 62 gamax

  const float FI   = (float)(1.0 / 1.1);
  const float FIM1 = (float)(1.0 / 1.1 - 1.0);
  const float TINY = 1.1920928955078125e-07f;
  const float PA   = 1.0f / 16384.0f;
  const float PBJ  = 0.5f / 1024.0f;
  const float PBL  = 0.5f;
  const float EPSF = 0.1f;

  // ---------------- init: softmax stats + Q0 (bf16) into LDS ----------------
  if (tid < CPB) {
    AS(&varr[g * CPB + tid], 0.0f);
    AS(&varr[VSTR + g * CPB + tid], 0.0f);
    wlds[tid] = 1.0f;
  }
  if (g == NBLK - 1 && tid == CPB) { AS(&varr[KC], 0.0f); AS(&varr[VSTR + KC], 0.0f); }
  bstage[tid] = 1.0f / 1025.0f;
  if (tid == 0) bstage[KC] = 1.0f / 1025.0f;
#pragma unroll
  for (int r = 0; r < RPW; ++r) {
    const int i  = row0 + r;
    const int lr = wv * RPW + r;
    const float* xr = X + (size_t)i * KC;
    float x[16];
    {
      const float4 t0 = *reinterpret_cast<const float4*>(xr + 8 * lane);
      const float4 t1 = *reinterpret_cast<const float4*>(xr + 8 * lane + 4);
      const float4 t2 = *reinterpret_cast<const float4*>(xr + 512 + 8 * lane);
      const float4 t3 = *reinterpret_cast<const float4*>(xr + 512 + 8 * lane + 4);
      x[0]=t0.x; x[1]=t0.y; x[2]=t0.z; x[3]=t0.w;
      x[4]=t1.x; x[5]=t1.y; x[6]=t1.z; x[7]=t1.w;
      x[8]=t2.x; x[9]=t2.y; x[10]=t2.z; x[11]=t2.w;
      x[12]=t3.x; x[13]=t3.y; x[14]=t3.z; x[15]=t3.w;
    }
    float mx = -INFINITY;
#pragma unroll
    for (int e = 0; e < 16; ++e) mx = fmaxf(mx, x[e]);
    mx = wave_max(mx);
    float s = 0.0f;
#pragma unroll
    for (int e = 0; e < 16; ++e) s += expf(x[e] - mx);
    s = wave_sum(s);
    const float L = logf(s);
    if (lane == 0) { rxm[lr] = mx; rlr[lr] = L; ru[lr] = 0.0f; rq[lr] = 1.0f; }
    float q[16];
#pragma unroll
    for (int e = 0; e < 16; ++e) q[e] = expf(((x[e] - mx) - L) / EPSF);
    uint4* qrow = (uint4*)(Qs + (size_t)lr * KC);
    qrow[lane]      = pack8(q);
    qrow[64 + lane] = pack8(q + 8);
  }
  __syncthreads();   // bstage + Qs ready (block-local; no global sync needed)

  // ---------------- main loop ----------------
  int vp = 0, stab = 0;
  unsigned seq = 0;

  for (int it = 0; it < NITER; ++it) {
    float zac[16];
#pragma unroll
    for (int e = 0; e < 16; ++e) zac[e] = 0.0f;
    float zl = 0.0f, amx = -INFINITY;

    float bf[16];
    {
      const float4 t0 = *reinterpret_cast<const float4*>(&bstage[8 * lane]);
      const float4 t1 = *reinterpret_cast<const float4*>(&bstage[8 * lane + 4]);
      const float4 t2 = *reinterpret_cast<const float4*>(&bstage[512 + 8 * lane]);
      const float4 t3 = *reinterpret_cast<const float4*>(&bstage[512 + 8 * lane + 4]);
      bf[0]=t0.x; bf[1]=t0.y; bf[2]=t0.z; bf[3]=t0.w;
      bf[4]=t1.x; bf[5]=t1.y; bf[6]=t1.z; bf[7]=t1.w;
      bf[8]=t2.x; bf[9]=t2.y; bf[10]=t2.z; bf[11]=t2.w;
      bf[12]=t3.x; bf[13]=t3.y; bf[14]=t3.z; bf[15]=t3.w;
    }
    const float bl = bstage[KC];

    if (!stab) {
      // ---- P1 from LDS: y = Q b ; a = Pa/y ; z += a_i * Q_i ----
#pragma unroll
      for (int r = 0; r < RPW; ++r) {
        const int lr = wv * RPW + r;
        const uint4* qrow = (const uint4*)(Qs + (size_t)lr * KC);
        const uint4 p0 = qrow[lane], p1 = qrow[64 + lane];
        float q[16];
        unpack8(p0, q); unpack8(p1, q + 8);
        float d = 0.0f;
#pragma unroll
        for (int e = 0; e < 16; ++e) d = fmaf(q[e], bf[e], d);
        const float ql = rq[lr];
        const float y  = wave_sum(d) + ql * bl;
        const float ai = PA / y;
        if (lane == 0) ra[lr] = ai;
        amx = fmaxf(amx, ai);
#pragma unroll
        for (int e = 0; e < 16; ++e) zac[e] = fmaf(ai, q[e], zac[e]);
        zl = fmaf(ai, ql, zl);
      }
    } else {
      // ---- P1 deferred stabilization: rewrite Q (LDS) from logits; b := ones ----
      if (tid < CPB) {
        const int j = g * CPB + tid;
        const float bj = bstage[j];
        AS(&varr[(vp ^ 1) * VSTR + j], AL(&varr[vp * VSTR + j]) + EPSF * logf(bj + TINY));
        wlds[tid] = wlds[tid] * powf(bj, FIM1);
      }
      if (g == NBLK - 1 && tid == CPB)
        AS(&varr[(vp ^ 1) * VSTR + KC], AL(&varr[vp * VSTR + KC]) + EPSF * logf(bstage[KC] + TINY));
      float v2f[16];
#pragma unroll
      for (int e = 0; e < 16; ++e) {
        const int j = (e < 8) ? (8 * lane + e) : (512 + 8 * lane + (e - 8));
        v2f[e] = AL(&varr[vp * VSTR + j]) + EPSF * logf(bstage[j] + TINY);
      }
      const float v2l = AL(&varr[vp * VSTR + KC]) + EPSF * logf(bstage[KC] + TINY);
#pragma unroll
      for (int r = 0; r < RPW; ++r) {
        const int i  = row0 + r;
        const int lr = wv * RPW + r;
        const float u2 = ru[lr] + EPSF * logf(ra[lr]);
        if (lane == 0) ru[lr] = u2;
        const float mi = rxm[lr], Li = rlr[lr];
        const float* xr = X + (size_t)i * KC;
        float q[16];
        {
          const float4 t0 = *reinterpret_cast<const float4*>(xr + 8 * lane);
          const float4 t1 = *reinterpret_cast<const float4*>(xr + 8 * lane + 4);
          const float4 t2 = *reinterpret_cast<const float4*>(xr + 512 + 8 * lane);
          const float4 t3 = *reinterpret_cast<const float4*>(xr + 512 + 8 * lane + 4);
          q[0]=t0.x; q[1]=t0.y; q[2]=t0.z; q[3]=t0.w;
          q[4]=t1.x; q[5]=t1.y; q[6]=t1.z; q[7]=t1.w;
          q[8]=t2.x; q[9]=t2.y; q[10]=t2.z; q[11]=t2.w;
          q[12]=t3.x; q[13]=t3.y; q[14]=t3.z; q[15]=t3.w;
        }
#pragma unroll
        for (int e = 0; e < 16; ++e) {
          const float cost = Li - (q[e] - mi);
          q[e] = expf((u2 - cost + v2f[e]) / EPSF);
        }
        uint4* qrow = (uint4*)(Qs + (size_t)lr * KC);
        qrow[lane]      = pack8(q);
        qrow[64 + lane] = pack8(q + 8);
        float d = 0.0f;
#pragma unroll
        for (int e = 0; e < 16; ++e) d += q[e];
        const float ql = expf((u2 + v2l) / EPSF);
        if (lane == 0) rq[lr] = ql;
        const float y  = wave_sum(d) + ql;
        const float ai = PA / y;
        if (lane == 0) ra[lr] = ai;
        amx = fmaxf(amx, ai);
#pragma unroll
        for (int e = 0; e < 16; ++e) zac[e] = fmaf(ai, q[e], zac[e]);
        zl = fmaf(ai, ql, zl);
      }
      vp ^= 1;
    }

    // ---- z reduce: 4-phase accumulate into zred[4][KC] (conflict-free layout) ----
    const float wamx = wave_max(amx);
    if (lane == 0) { ldss[wv] = zl; ldss[16 + wv] = wamx; }
    float* zrow = zred + (wv & 3) * KC;
    const int gp = wv >> 2;
    __syncthreads();
    if (gp == 0) {
      *reinterpret_cast<float4*>(&zrow[lane * 4])       = make_float4(zac[0], zac[1], zac[2], zac[3]);
      *reinterpret_cast<float4*>(&zrow[256 + lane * 4]) = make_float4(zac[4], zac[5], zac[6], zac[7]);
      *reinterpret_cast<float4*>(&zrow[512 + lane * 4]) = make_float4(zac[8], zac[9], zac[10], zac[11]);
      *reinterpret_cast<float4*>(&zrow[768 + lane * 4]) = make_float4(zac[12], zac[13], zac[14], zac[15]);
    }
    __syncthreads();
#pragma unroll
    for (int p = 1; p < 4; ++p) {
      if (gp == p) {
        float4 t;
        t = *reinterpret_cast<float4*>(&zrow[lane * 4]);
        t.x += zac[0]; t.y += zac[1]; t.z += zac[2]; t.w += zac[3];
        *reinterpret_cast<float4*>(&zrow[lane * 4]) = t;
        t = *reinterpret_cast<float4*>(&zrow[256 + lane * 4]);
        t.x += zac[4]; t.y += zac[5]; t.z += zac[6]; t.w += zac[7];
        *reinterpret_cast<float4*>(&zrow[256 + lane * 4]) = t;
        t = *reinterpret_cast<float4*>(&zrow[512 + lane * 4]);
        t.x += zac[8]; t.y += zac[9]; t.z += zac[10]; t.w += zac[11];
        *reinterpret_cast<float4*>(&zrow[512 + lane * 4]) = t;
        t = *reinterpret_cast<float4*>(&zrow[768 + lane * 4]);
        t.x += zac[12]; t.y += zac[13]; t.z += zac[14]; t.w += zac[15];
        *reinterpret_cast<float4*>(&zrow[768 + lane * 4]) = t;
      }
      __syncthreads();
    }
    {
      const int wi   = tid & 511;
      const int fidx = ((tid >> 9) * 2 + ((wi & 7) >> 2)) * 256 + (wi >> 3) * 4 + (wi & 3);
      const float s = ((zred[fidx] + zred[KC + fidx]) + zred[2 * KC + fidx]) + zred[3 * KC + fidx];
      AS(&zpart[(size_t)g * VSTR + tid], s);
    }
    float blkamax = 0.0f;
    if (tid == 0) {
      float zt = 0.0f;
#pragma unroll
      for (int w = 0; w < 16; ++w) zt += ldss[w];
      AS(&zpart[(size_t)g * VSTR + KC], zt);
      float am = ldss[16];
#pragma unroll
      for (int w = 1; w < 16; ++w) am = fmaxf(am, ldss[16 + w]);
      blkamax = am;
      ldss[61] = am;            // master uses this for its own contribution
    }

    // ---- barrier 1: arrivals carry block amax; release carries global amax ----
    ++seq;
    __syncthreads();
    if (g == 0) {
      float pv = -INFINITY;
      if (tid >= 1 && tid < NBLK) {
        unsigned long long av;
        for (;;) {                       // busy spin: 255 pollers, private words
          av = AL(&arr[tid]);
          if ((unsigned)(av >> 32) >= seq) break;
        }
        pv = PAYOF(av);
      }
      if (tid < NBLK) {
        pv = wave_max(pv);
        if (lane == 0) ldss[56 + wv] = pv;
      }
      __syncthreads();   // all arrivals observed; ldss[56..59], ldss[61] ready
      if (tid < NBLK) {
        const float gm = fmaxf(fmaxf(fmaxf(ldss[56], ldss[57]),
                                     fmaxf(ldss[58], ldss[59])), ldss[61]);
        AS(&rel64[tid * 4], MKTAG(seq, gm));   // parallel release fan-out
        if (tid == 0) ldss[62] = gm;
      }
    } else {
      if (tid == 0) {
        asm volatile("s_waitcnt vmcnt(0)" ::: "memory");  // zpart visible before arrival
        AS(&arr[g], MKTAG(seq, blkamax));
        unsigned long long rv;
        for (;;) {                       // busy spin: private release line
          rv = AL(&rel64[g * 4]);
          if ((unsigned)(rv >> 32) >= seq) break;
        }
        ldss[62] = PAYOF(rv);
      }
      __syncthreads();
    }

    // ---- P2: owned columns -> tagged b, replicated 8x (paired u64 gather) ----
    if (tid < 256) {
      const unsigned long long* zb =
        (const unsigned long long*)(zpart + (size_t)tid * VSTR + g * CPB);
      const unsigned long long p01 = AL(zb), p23 = AL(zb + 1);
      const float s0 = wave_sum(__uint_as_float((unsigned)(p01 & 0xffffffffull)));
      const float s1 = wave_sum(__uint_as_float((unsigned)(p01 >> 32)));
      const float s2 = wave_sum(__uint_as_float((unsigned)(p23 & 0xffffffffull)));
      const float s3 = wave_sum(__uint_as_float((unsigned)(p23 >> 32)));
      float sl = 0.0f;
      if (g == NBLK - 1) sl = wave_sum(AL(zpart + (size_t)tid * VSTR + KC));
      if (lane == 0) {
        ldss[32 + wv * 4 + 0] = s0; ldss[32 + wv * 4 + 1] = s1;
        ldss[32 + wv * 4 + 2] = s2; ldss[32 + wv * 4 + 3] = s3;
        ldss[48 + wv] = sl;
      }
    }
    __syncthreads();
    if (tid == 0) {
#pragma unroll
      for (int c = 0; c < CPB; ++c) {
        const float z    = ((ldss[32 + c] + ldss[36 + c]) + ldss[40 + c]) + ldss[44 + c];
        const float bnew = powf(PBJ / z, FI) * wlds[c];
        const unsigned long long tv = MKTAG(seq, bnew);
#pragma unroll
        for (int rep = 0; rep < 8; ++rep) AS(&brep64[(size_t)rep * BSTR + g * CPB + c], tv);
      }
      if (g == NBLK - 1) {
        const float z  = ((ldss[48] + ldss[49]) + ldss[50]) + ldss[51];
        const float bn = PBL / z;
        const unsigned long long tv = MKTAG(seq, bn);
#pragma unroll
        for (int rep = 0; rep < 8; ++rep) AS(&brep64[(size_t)rep * BSTR + KC], tv);
      }
    }

    // ---- tagged-b consume: poll == seq, stage to LDS, stab from gamax/bmax ----
    {
      unsigned long long v;
      for (;;) {
        v = AL(&myrep[tid]);
        if (TAGOF(v) == seq) break;
        __builtin_amdgcn_s_sleep(2);
      }
      const float bv = PAYOF(v);
      bstage[tid] = bv;
      if (tid == 0) {
        for (;;) {
          v = AL(&myrep[KC]);
          if (TAGOF(v) == seq) break;
          __builtin_amdgcn_s_sleep(2);
        }
        bstage[KC] = PAYOF(v);
      }
      const float wm = wave_max(bv);
      if (lane == 0) ldss[wv] = wm;
      __syncthreads();   // bstage + ldss[0..15] + ldss[62] ready
      float bmx = ldss[0];
#pragma unroll
      for (int w = 1; w < 16; ++w) bmx = fmaxf(bmx, ldss[w]);
      bmx = fmaxf(bmx, bstage[KC]);
      stab = (fmaxf(ldss[62], bmx) > 1e8f) ? 1 : 0;
    }
  }

  // ---------------- epilogue (bstage/stab from final iteration) ----------------
  if (!stab) {
    // plan = n * a_i * Qs_ij * b_j   (Q from LDS; single pass)
    float bf[16];
    {
      const float4 t0 = *reinterpret_cast<const float4*>(&bstage[8 * lane]);
      const float4 t1 = *reinterpret_cast<const float4*>(&bstage[8 * lane + 4]);
      const float4 t2 = *reinterpret_cast<const float4*>(&bstage[512 + 8 * lane]);
      const float4 t3 = *reinterpret_cast<const float4*>(&bstage[512 + 8 * lane + 4]);
      bf[0]=t0.x; bf[1]=t0.y; bf[2]=t0.z; bf[3]=t0.w;
      bf[4]=t1.x; bf[5]=t1.y; bf[6]=t1.z; bf[7]=t1.w;
      bf[8]=t2.x; bf[9]=t2.y; bf[10]=t2.z; bf[11]=t2.w;
      bf[12]=t3.x; bf[13]=t3.y; bf[14]=t3.z; bf[15]=t3.w;
    }
#pragma unroll
    for (int r = 0; r < RPW; ++r) {
      const int i  = row0 + r;
      const int lr = wv * RPW + r;
      const float an = ra[lr] * 16384.0f;
      const uint4* qrow = (const uint4*)(Qs + (size_t)lr * KC);
      const uint4 p0 = qrow[lane], p1 = qrow[64 + lane];
      float q[16];
      unpack8(p0, q); unpack8(p1, q + 8);
      float* orow = Qf + (size_t)i * KC;
      *reinterpret_cast<float4*>(orow + 8 * lane) =
        make_float4(an*q[0]*bf[0], an*q[1]*bf[1], an*q[2]*bf[2], an*q[3]*bf[3]);
      *reinterpret_cast<float4*>(orow + 8 * lane + 4) =
        make_float4(an*q[4]*bf[4], an*q[5]*bf[5], an*q[6]*bf[6], an*q[7]*bf[7]);
      *reinterpret_cast<float4*>(orow + 512 + 8 * lane) =
        make_float4(an*q[8]*bf[8], an*q[9]*bf[9], an*q[10]*bf[10], an*q[11]*bf[11]);
      *reinterpret_cast<float4*>(orow + 512 + 8 * lane + 4) =
        make_float4(an*q[12]*bf[12], an*q[13]*bf[13], an*q[14]*bf[14], an*q[15]*bf[15]);
    }
  } else {
    // pending stabilization at exit: plan = n * exp((u2 - cost + v2^T)/eps), from X
    float v2f[16];
#pragma unroll
    for (int e = 0; e < 16; ++e) {
      const int j = (e < 8) ? (8 * lane + e) : (512 + 8 * lane + (e - 8));
      v2f[e] = AL(&varr[vp * VSTR + j]) + EPSF * logf(bstage[j] + TINY);
    }
#pragma unroll
    for (int r = 0; r < RPW; ++r) {
      const int i  = row0 + r;
      const int lr = wv * RPW + r;
      const float u2 = ru[lr] + EPSF * logf(ra[lr]);
      const float mi = rxm[lr], Li = rlr[lr];
      const float* xr = X + (size_t)i * KC;
      float x[16];
      {
        const float4 t0 = *reinterpret_cast<const float4*>(xr + 8 * lane);
        const float4 t1 = *reinterpret_cast<const float4*>(xr + 8 * lane + 4);
        const float4 t2 = *reinterpret_cast<const float4*>(xr + 512 + 8 * lane);
        const float4 t3 = *reinterpret_cast<const float4*>(xr + 512 + 8 * lane + 4);
        x[0]=t0.x; x[1]=t0.y; x[2]=t0.z; x[3]=t0.w;
        x[4]=t1.x; x[5]=t1.y; x[6]=t1.z; x[7]=t1.w;
        x[8]=t2.x; x[9]=t2.y; x[10]=t2.z; x[11]=t2.w;
        x[12]=t3.x; x[13]=t3.y; x[14]=t3.z; x[15]=t3.w;
      }
      float q[16];
#pragma unroll
      for (int e = 0; e < 16; ++e)
        q[e] = expf((u2 - (Li - (x[e] - mi)) + v2f[e]) / EPSF) * 16384.0f;
      float* orow = Qf + (size_t)i * KC;
      *reinterpret_cast<float4*>(orow + 8 * lane)           = make_float4(q[0], q[1], q[2], q[3]);
      *reinterpret_cast<float4*>(orow + 8 * lane + 4)       = make_float4(q[4], q[5], q[6], q[7]);
      *reinterpret_cast<float4*>(orow + 512 + 8 * lane)     = make_float4(q[8], q[9], q[10], q[11]);
      *reinterpret_cast<float4*>(orow + 512 + 8 * lane + 4) = make_float4(q[12], q[13], q[14], q[15]);
    }
  }
}

extern "C" void kernel_launch(void* const* d_in, const int* in_sizes, int n_in,
                              void* d_out, int out_size, void* d_ws, size_t ws_size,
                              hipStream_t stream)
{
  (void)in_sizes; (void)n_in; (void)out_size; (void)ws_size;
  const float* X = (const float*)d_in[0];
  float* Qf = (float*)d_out;
  hipMemsetAsync(d_ws, 0, 16384, stream);   // arr + rel64 (tagged-b uses equality polls)
  void* args[3] = { (void*)&X, (void*)&Qf, (void*)&d_ws };
  hipLaunchCooperativeKernel((const void*)sk_coop, dim3(NBLK), dim3(NTHR),
                             args, 0, stream);
}

// Round 14
// 5057.436 us; speedup vs baseline: 3.3005x; 2.6418x over previous
//
#include <hip/hip_runtime.h>
#include <math.h>

#define NROWS 16384
#define KC    1024
#define NBLK  256
#define NTHR  1024
#define WPB   16      // waves per block
#define RPW   4       // rows per wave; 64 rows per block
#define CPB   4       // regular columns owned per block (block 255 also owns col 1024)
#define VSTR  1056    // padded stride for varr / zpart
#define BSTR  1088    // u64 stride for tagged-b replicas
#define NITER 1000

// relaxed agent-scope (device-coherent) access
#define AL(p)    __hip_atomic_load((p), __ATOMIC_RELAXED, __HIP_MEMORY_SCOPE_AGENT)
#define AS(p,v)  __hip_atomic_store((p), (v), __ATOMIC_RELAXED, __HIP_MEMORY_SCOPE_AGENT)

__device__ __forceinline__ float wave_sum(float v) {
#pragma unroll
  for (int o = 32; o > 0; o >>= 1) v += __shfl_xor(v, o, 64);
  return v;
}
__device__ __forceinline__ float wave_max(float v) {
#pragma unroll
  for (int o = 32; o > 0; o >>= 1) v = fmaxf(v, __shfl_xor(v, o, 64));
  return v;
}

// bf16 pack/unpack (RNE)
__device__ __forceinline__ unsigned short f2b(float f) {
  unsigned u = __float_as_uint(f);
  u += 0x7FFFu + ((u >> 16) & 1u);
  return (unsigned short)(u >> 16);
}
__device__ __forceinline__ float b2f(unsigned h) {
  return __uint_as_float(h << 16);
}
__device__ __forceinline__ void unpack8(const uint4 p, float* f) {
  f[0] = b2f(p.x & 0xffffu); f[1] = b2f(p.x >> 16);
  f[2] = b2f(p.y & 0xffffu); f[3] = b2f(p.y >> 16);
  f[4] = b2f(p.z & 0xffffu); f[5] = b2f(p.z >> 16);
  f[6] = b2f(p.w & 0xffffu); f[7] = b2f(p.w >> 16);
}
__device__ __forceinline__ uint4 pack8(const float* f) {
  uint4 p;
  p.x = (unsigned)f2b(f[0]) | ((unsigned)f2b(f[1]) << 16);
  p.y = (unsigned)f2b(f[2]) | ((unsigned)f2b(f[3]) << 16);
  p.z = (unsigned)f2b(f[4]) | ((unsigned)f2b(f[5]) << 16);
  p.w = (unsigned)f2b(f[6]) | ((unsigned)f2b(f[7]) << 16);
  return p;
}

#define TAGOF(v)  ((unsigned)((v) >> 32))
#define PAYOF(v)  (__uint_as_float((unsigned)((v) & 0xffffffffull)))
#define MKTAG(s,f) (((unsigned long long)(s) << 32) | (unsigned long long)__float_as_uint(f))

// ws layout:
//   u64 arr[256]     @ 0      arrival: hi=seq, lo=float(block amax)   [memset 0]
//   u64 rel64[256*4] @ 2048   per-block release (32B apart): hi=seq, lo=float(gamax) [memset 0]
//   floats           @ 16384  varr[2*VSTR], zpart[NBLK][VSTR]
//   u64 brep64[8][BSTR] after zpart: tagged b, hi=seq (equality-polled), lo=f32 bits

// Lane-column mapping: lane l owns cols [8l, 8l+8) and [512+8l, 512+8l+8).
// zred row layout (1024 floats): chunk k (0..3) at [k*256 + lane*4 .. +3].
__global__ __launch_bounds__(NTHR, 4)
void sk_coop(const float* __restrict__ X, float* __restrict__ Qf, void* __restrict__ wsv)
{
  const int g    = blockIdx.x;
  const int tid  = threadIdx.x;
  const int wv   = tid >> 6;
  const int lane = tid & 63;
  const int row0 = (g * WPB + wv) * RPW;   // global row base for this wave

  unsigned long long* arr   = (unsigned long long*)wsv;                  // [256]
  unsigned long long* rel64 = (unsigned long long*)((char*)wsv + 2048);  // [256*4]
  float* varr  = (float*)((char*)wsv + 16384);                           // [2*VSTR]
  float* zpart = varr + 2 * VSTR;                                        // [NBLK][VSTR]
  unsigned long long* brep64 = (unsigned long long*)(zpart + (size_t)NBLK * VSTR);
  unsigned long long* myrep  = brep64 + (size_t)(((unsigned)g) & 7u) * BSTR;

  // ---- LDS: whole Q tile resident across the loop (131 KB) ----
  __shared__ unsigned short Qs[64 * KC];      // bf16, row lr at Qs + lr*KC
  __shared__ float zred[4 * KC];              // 16 KB z accumulate (4 rows)
  __shared__ float bstage[VSTR];              // persists across iterations (= last_b)
  __shared__ float rq[64], rxm[64], rlr[64], ra[64], ru[64];  // per-local-row state
  __shared__ float wlds[CPB];
  __shared__ float ldss[64];   // 0..15 bmax / z-reduce, 16..31 err / amax, 32..55 P2, 56..59 sweep, 61 blkamax, 62 gamax

  const float FI   = (float)(1.0 / 1.1);
  const float FIM1 = (float)(1.0 / 1.1 - 1.0);
  const float TINY = 1.1920928955078125e-07f;
  const float PA   = 1.0f / 16384.0f;
  const float PBJ  = 0.5f / 1024.0f;
  const float PBL  = 0.5f;
  const float EPSF = 0.1f;

  // ---------------- init: softmax stats + Q0 (bf16) into LDS ----------------
  if (tid < CPB) {
    AS(&varr[g * CPB + tid], 0.0f);
    AS(&varr[VSTR + g * CPB + tid], 0.0f);
    wlds[tid] = 1.0f;
  }
  if (g == NBLK - 1 && tid == CPB) { AS(&varr[KC], 0.0f); AS(&varr[VSTR + KC], 0.0f); }
  bstage[tid] = 1.0f / 1025.0f;
  if (tid == 0) bstage[KC] = 1.0f / 1025.0f;
#pragma unroll
  for (int r = 0; r < RPW; ++r) {
    const int i  = row0 + r;
    const int lr = wv * RPW + r;
    const float* xr = X + (size_t)i * KC;
    float x[16];
    {
      const float4 t0 = *reinterpret_cast<const float4*>(xr + 8 * lane);
      const float4 t1 = *reinterpret_cast<const float4*>(xr + 8 * lane + 4);
      const float4 t2 = *reinterpret_cast<const float4*>(xr + 512 + 8 * lane);
      const float4 t3 = *reinterpret_cast<const float4*>(xr + 512 + 8 * lane + 4);
      x[0]=t0.x; x[1]=t0.y; x[2]=t0.z; x[3]=t0.w;
      x[4]=t1.x; x[5]=t1.y; x[6]=t1.z; x[7]=t1.w;
      x[8]=t2.x; x[9]=t2.y; x[10]=t2.z; x[11]=t2.w;
      x[12]=t3.x; x[13]=t3.y; x[14]=t3.z; x[15]=t3.w;
    }
    float mx = -INFINITY;
#pragma unroll
    for (int e = 0; e < 16; ++e) mx = fmaxf(mx, x[e]);
    mx = wave_max(mx);
    float s = 0.0f;
#pragma unroll
    for (int e = 0; e < 16; ++e) s += expf(x[e] - mx);
    s = wave_sum(s);
    const float L = logf(s);
    if (lane == 0) { rxm[lr] = mx; rlr[lr] = L; ru[lr] = 0.0f; rq[lr] = 1.0f; }
    float q[16];
#pragma unroll
    for (int e = 0; e < 16; ++e) q[e] = expf(((x[e] - mx) - L) / EPSF);
    uint4* qrow = (uint4*)(Qs + (size_t)lr * KC);
    qrow[lane]      = pack8(q);
    qrow[64 + lane] = pack8(q + 8);
  }
  __syncthreads();   // bstage + Qs ready (block-local; no global sync needed)

  // ---------------- main loop ----------------
  int vp = 0, stab = 0;
  unsigned seq = 0;

  for (int it = 0; it < NITER; ++it) {
    float zac[16];
#pragma unroll
    for (int e = 0; e < 16; ++e) zac[e] = 0.0f;
    float zl = 0.0f, amx = -INFINITY;

    float bf[16];
    {
      const float4 t0 = *reinterpret_cast<const float4*>(&bstage[8 * lane]);
      const float4 t1 = *reinterpret_cast<const float4*>(&bstage[8 * lane + 4]);
      const float4 t2 = *reinterpret_cast<const float4*>(&bstage[512 + 8 * lane]);
      const float4 t3 = *reinterpret_cast<const float4*>(&bstage[512 + 8 * lane + 4]);
      bf[0]=t0.x; bf[1]=t0.y; bf[2]=t0.z; bf[3]=t0.w;
      bf[4]=t1.x; bf[5]=t1.y; bf[6]=t1.z; bf[7]=t1.w;
      bf[8]=t2.x; bf[9]=t2.y; bf[10]=t2.z; bf[11]=t2.w;
      bf[12]=t3.x; bf[13]=t3.y; bf[14]=t3.z; bf[15]=t3.w;
    }
    const float bl = bstage[KC];

    if (!stab) {
      // ---- P1 from LDS: y = Q b ; a = Pa/y ; z += a_i * Q_i ----
#pragma unroll
      for (int r = 0; r < RPW; ++r) {
        const int lr = wv * RPW + r;
        const uint4* qrow = (const uint4*)(Qs + (size_t)lr * KC);
        const uint4 p0 = qrow[lane], p1 = qrow[64 + lane];
        float q[16];
        unpack8(p0, q); unpack8(p1, q + 8);
        float d = 0.0f;
#pragma unroll
        for (int e = 0; e < 16; ++e) d = fmaf(q[e], bf[e], d);
        const float ql = rq[lr];
        const float y  = wave_sum(d) + ql * bl;
        const float ai = PA / y;
        if (lane == 0) ra[lr] = ai;
        amx = fmaxf(amx, ai);
#pragma unroll
        for (int e = 0; e < 16; ++e) zac[e] = fmaf(ai, q[e], zac[e]);
        zl = fmaf(ai, ql, zl);
      }
    } else {
      // ---- P1 deferred stabilization: rewrite Q (LDS) from logits; b := ones ----
      if (tid < CPB) {
        const int j = g * CPB + tid;
        const float bj = bstage[j];
        AS(&varr[(vp ^ 1) * VSTR + j], AL(&varr[vp * VSTR + j]) + EPSF * logf(bj + TINY));
        wlds[tid] = wlds[tid] * powf(bj, FIM1);
      }
      if (g == NBLK - 1 && tid == CPB)
        AS(&varr[(vp ^ 1) * VSTR + KC], AL(&varr[vp * VSTR + KC]) + EPSF * logf(bstage[KC] + TINY));
      float v2f[16];
#pragma unroll
      for (int e = 0; e < 16; ++e) {
        const int j = (e < 8) ? (8 * lane + e) : (512 + 8 * lane + (e - 8));
        v2f[e] = AL(&varr[vp * VSTR + j]) + EPSF * logf(bstage[j] + TINY);
      }
      const float v2l = AL(&varr[vp * VSTR + KC]) + EPSF * logf(bstage[KC] + TINY);
#pragma unroll
      for (int r = 0; r < RPW; ++r) {
        const int i  = row0 + r;
        const int lr = wv * RPW + r;
        const float u2 = ru[lr] + EPSF * logf(ra[lr]);
        if (lane == 0) ru[lr] = u2;
        const float mi = rxm[lr], Li = rlr[lr];
        const float* xr = X + (size_t)i * KC;
        float q[16];
        {
          const float4 t0 = *reinterpret_cast<const float4*>(xr + 8 * lane);
          const float4 t1 = *reinterpret_cast<const float4*>(xr + 8 * lane + 4);
          const float4 t2 = *reinterpret_cast<const float4*>(xr + 512 + 8 * lane);
          const float4 t3 = *reinterpret_cast<const float4*>(xr + 512 + 8 * lane + 4);
          q[0]=t0.x; q[1]=t0.y; q[2]=t0.z; q[3]=t0.w;
          q[4]=t1.x; q[5]=t1.y; q[6]=t1.z; q[7]=t1.w;
          q[8]=t2.x; q[9]=t2.y; q[10]=t2.z; q[11]=t2.w;
          q[12]=t3.x; q[13]=t3.y; q[14]=t3.z; q[15]=t3.w;
        }
#pragma unroll
        for (int e = 0; e < 16; ++e) {
          const float cost = Li - (q[e] - mi);
          q[e] = expf((u2 - cost + v2f[e]) / EPSF);
        }
        uint4* qrow = (uint4*)(Qs + (size_t)lr * KC);
        qrow[lane]      = pack8(q);
        qrow[64 + lane] = pack8(q + 8);
        float d = 0.0f;
#pragma unroll
        for (int e = 0; e < 16; ++e) d += q[e];
        const float ql = expf((u2 + v2l) / EPSF);
        if (lane == 0) rq[lr] = ql;
        const float y  = wave_sum(d) + ql;
        const float ai = PA / y;
        if (lane == 0) ra[lr] = ai;
        amx = fmaxf(amx, ai);
#pragma unroll
        for (int e = 0; e < 16; ++e) zac[e] = fmaf(ai, q[e], zac[e]);
        zl = fmaf(ai, ql, zl);
      }
      vp ^= 1;
    }

    // ---- z reduce: 4-phase accumulate into zred[4][KC] (conflict-free layout) ----
    const float wamx = wave_max(amx);
    if (lane == 0) { ldss[wv] = zl; ldss[16 + wv] = wamx; }
    float* zrow = zred + (wv & 3) * KC;
    const int gp = wv >> 2;
    __syncthreads();
    if (gp == 0) {
      *reinterpret_cast<float4*>(&zrow[lane * 4])       = make_float4(zac[0], zac[1], zac[2], zac[3]);
      *reinterpret_cast<float4*>(&zrow[256 + lane * 4]) = make_float4(zac[4], zac[5], zac[6], zac[7]);
      *reinterpret_cast<float4*>(&zrow[512 + lane * 4]) = make_float4(zac[8], zac[9], zac[10], zac[11]);
      *reinterpret_cast<float4*>(&zrow[768 + lane * 4]) = make_float4(zac[12], zac[13], zac[14], zac[15]);
    }
    __syncthreads();
#pragma unroll
    for (int p = 1; p < 4; ++p) {
      if (gp == p) {
        float4 t;
        t = *reinterpret_cast<float4*>(&zrow[lane * 4]);
        t.x += zac[0]; t.y += zac[1]; t.z += zac[2]; t.w += zac[3];
        *reinterpret_cast<float4*>(&zrow[lane * 4]) = t;
        t = *reinterpret_cast<float4*>(&zrow[256 + lane * 4]);
        t.x += zac[4]; t.y += zac[5]; t.z += zac[6]; t.w += zac[7];
        *reinterpret_cast<float4*>(&zrow[256 + lane * 4]) = t;
        t = *reinterpret_cast<float4*>(&zrow[512 + lane * 4]);
        t.x += zac[8]; t.y += zac[9]; t.z += zac[10]; t.w += zac[11];
        *reinterpret_cast<float4*>(&zrow[512 + lane * 4]) = t;
        t = *reinterpret_cast<float4*>(&zrow[768 + lane * 4]);
        t.x += zac[12]; t.y += zac[13]; t.z += zac[14]; t.w += zac[15];
        *reinterpret_cast<float4*>(&zrow[768 + lane * 4]) = t;
      }
      __syncthreads();
    }
    {
      const int wi   = tid & 511;
      const int fidx = ((tid >> 9) * 2 + ((wi & 7) >> 2)) * 256 + (wi >> 3) * 4 + (wi & 3);
      const float s = ((zred[fidx] + zred[KC + fidx]) + zred[2 * KC + fidx]) + zred[3 * KC + fidx];
      AS(&zpart[(size_t)g * VSTR + tid], s);
    }
    float blkamax = 0.0f;
    if (tid == 0) {
      float zt = 0.0f;
#pragma unroll
      for (int w = 0; w < 16; ++w) zt += ldss[w];
      AS(&zpart[(size_t)g * VSTR + KC], zt);
      float am = ldss[16];
#pragma unroll
      for (int w = 1; w < 16; ++w) am = fmaxf(am, ldss[16 + w]);
      blkamax = am;
      ldss[61] = am;            // master uses this for its own contribution
    }

    // ---- barrier 1: arrivals carry block amax; release carries global amax ----
    ++seq;
    __syncthreads();
    if (g == 0) {
      float pv = -INFINITY;
      if (tid >= 1 && tid < NBLK) {
        unsigned long long av;
        for (;;) {                       // busy spin: 255 pollers, private words
          av = AL(&arr[tid]);
          if ((unsigned)(av >> 32) >= seq) break;
        }
        pv = PAYOF(av);
      }
      if (tid < NBLK) {
        pv = wave_max(pv);
        if (lane == 0) ldss[56 + wv] = pv;
      }
      __syncthreads();   // all arrivals observed; ldss[56..59], ldss[61] ready
      if (tid < NBLK) {
        const float gm = fmaxf(fmaxf(fmaxf(ldss[56], ldss[57]),
                                     fmaxf(ldss[58], ldss[59])), ldss[61]);
        AS(&rel64[tid * 4], MKTAG(seq, gm));   // parallel release fan-out
        if (tid == 0) ldss[62] = gm;
      }
    } else {
      if (tid == 0) {
        asm volatile("s_waitcnt vmcnt(0)" ::: "memory");  // zpart visible before arrival
        AS(&arr[g], MKTAG(seq, blkamax));
        unsigned long long rv;
        for (;;) {                       // busy spin: private release line
          rv = AL(&rel64[g * 4]);
          if ((unsigned)(rv >> 32) >= seq) break;
        }
        ldss[62] = PAYOF(rv);
      }
      __syncthreads();
    }

    // ---- P2: owned columns -> tagged b, replicated 8x (paired u64 gather) ----
    if (tid < 256) {
      const unsigned long long* zb =
        (const unsigned long long*)(zpart + (size_t)tid * VSTR + g * CPB);
      const unsigned long long p01 = AL(zb), p23 = AL(zb + 1);
      const float s0 = wave_sum(__uint_as_float((unsigned)(p01 & 0xffffffffull)));
      const float s1 = wave_sum(__uint_as_float((unsigned)(p01 >> 32)));
      const float s2 = wave_sum(__uint_as_float((unsigned)(p23 & 0xffffffffull)));
      const float s3 = wave_sum(__uint_as_float((unsigned)(p23 >> 32)));
      float sl = 0.0f;
      if (g == NBLK - 1) sl = wave_sum(AL(zpart + (size_t)tid * VSTR + KC));
      if (lane == 0) {
        ldss[32 + wv * 4 + 0] = s0; ldss[32 + wv * 4 + 1] = s1;
        ldss[32 + wv * 4 + 2] = s2; ldss[32 + wv * 4 + 3] = s3;
        ldss[48 + wv] = sl;
      }
    }
    __syncthreads();
    if (tid == 0) {
#pragma unroll
      for (int c = 0; c < CPB; ++c) {
        const float z    = ((ldss[32 + c] + ldss[36 + c]) + ldss[40 + c]) + ldss[44 + c];
        const float bnew = powf(PBJ / z, FI) * wlds[c];
        const unsigned long long tv = MKTAG(seq, bnew);
#pragma unroll
        for (int rep = 0; rep < 8; ++rep) AS(&brep64[(size_t)rep * BSTR + g * CPB + c], tv);
      }
      if (g == NBLK - 1) {
        const float z  = ((ldss[48] + ldss[49]) + ldss[50]) + ldss[51];
        const float bn = PBL / z;
        const unsigned long long tv = MKTAG(seq, bn);
#pragma unroll
        for (int rep = 0; rep < 8; ++rep) AS(&brep64[(size_t)rep * BSTR + KC], tv);
      }
    }

    // ---- tagged-b consume: poll == seq; err vs last_b (reference stop test) ----
    {
      unsigned long long v;
      for (;;) {
        v = AL(&myrep[tid]);
        if (TAGOF(v) == seq) break;
        __builtin_amdgcn_s_sleep(2);
      }
      const float bv = PAYOF(v);
      const float db = bv - bstage[tid];   // own slot: no race, read-before-write
      float e2 = db * db;
      bstage[tid] = bv;
      if (tid == 0) {
        for (;;) {
          v = AL(&myrep[KC]);
          if (TAGOF(v) == seq) break;
          __builtin_amdgcn_s_sleep(2);
        }
        const float bk = PAYOF(v);
        const float dk = bk - bstage[KC];
        e2 += dk * dk;
        bstage[KC] = bk;
      }
      const float wm = wave_max(bv);
      const float we = wave_sum(e2);
      if (lane == 0) { ldss[wv] = wm; ldss[16 + wv] = we; }
      __syncthreads();   // bstage + ldss[0..31] + ldss[62] ready
      float bmx = ldss[0];
      float er2 = ldss[16];
#pragma unroll
      for (int w = 1; w < 16; ++w) { bmx = fmaxf(bmx, ldss[w]); er2 += ldss[16 + w]; }
      bmx = fmaxf(bmx, bstage[KC]);
      stab = (fmaxf(ldss[62], bmx) > 1e8f) ? 1 : 0;
      // reference: while (err > 1e-10 && it < 1000); identical bits in every
      // block (same payloads, same fold order) -> uniform, deterministic break
      if (er2 <= 1e-20f) break;
    }
  }

  // ---------------- epilogue (bstage/stab from final iteration) ----------------
  if (!stab) {
    // plan = n * a_i * Qs_ij * b_j   (Q from LDS; single pass)
    float bf[16];
    {
      const float4 t0 = *reinterpret_cast<const float4*>(&bstage[8 * lane]);
      const float4 t1 = *reinterpret_cast<const float4*>(&bstage[8 * lane + 4]);
      const float4 t2 = *reinterpret_cast<const float4*>(&bstage[512 + 8 * lane]);
      const float4 t3 = *reinterpret_cast<const float4*>(&bstage[512 + 8 * lane + 4]);
      bf[0]=t0.x; bf[1]=t0.y; bf[2]=t0.z; bf[3]=t0.w;
      bf[4]=t1.x; bf[5]=t1.y; bf[6]=t1.z; bf[7]=t1.w;
      bf[8]=t2.x; bf[9]=t2.y; bf[10]=t2.z; bf[11]=t2.w;
      bf[12]=t3.x; bf[13]=t3.y; bf[14]=t3.z; bf[15]=t3.w;
    }
#pragma unroll
    for (int r = 0; r < RPW; ++r) {
      const int i  = row0 + r;
      const int lr = wv * RPW + r;
      const float an = ra[lr] * 16384.0f;
      const uint4* qrow = (const uint4*)(Qs + (size_t)lr * KC);
      const uint4 p0 = qrow[lane], p1 = qrow[64 + lane];
      float q[16];
      unpack8(p0, q); unpack8(p1, q + 8);
      float* orow = Qf + (size_t)i * KC;
      *reinterpret_cast<float4*>(orow + 8 * lane) =
        make_float4(an*q[0]*bf[0], an*q[1]*bf[1], an*q[2]*bf[2], an*q[3]*bf[3]);
      *reinterpret_cast<float4*>(orow + 8 * lane + 4) =
        make_float4(an*q[4]*bf[4], an*q[5]*bf[5], an*q[6]*bf[6], an*q[7]*bf[7]);
      *reinterpret_cast<float4*>(orow + 512 + 8 * lane) =
        make_float4(an*q[8]*bf[8], an*q[9]*bf[9], an*q[10]*bf[10], an*q[11]*bf[11]);
      *reinterpret_cast<float4*>(orow + 512 + 8 * lane + 4) =
        make_float4(an*q[12]*bf[12], an*q[13]*bf[13], an*q[14]*bf[14], an*q[15]*bf[15]);
    }
  } else {
    // pending stabilization at exit: plan = n * exp((u2 - cost + v2^T)/eps), from X
    float v2f[16];
#pragma unroll
    for (int e = 0; e < 16; ++e) {
      const int j = (e < 8) ? (8 * lane + e) : (512 + 8 * lane + (e - 8));
      v2f[e] = AL(&varr[vp * VSTR + j]) + EPSF * logf(bstage[j] + TINY);
    }
#pragma unroll
    for (int r = 0; r < RPW; ++r) {
      const int i  = row0 + r;
      const int lr = wv * RPW + r;
      const float u2 = ru[lr] + EPSF * logf(ra[lr]);
      const float mi = rxm[lr], Li = rlr[lr];
      const float* xr = X + (size_t)i * KC;
      float x[16];
      {
        const float4 t0 = *reinterpret_cast<const float4*>(xr + 8 * lane);
        const float4 t1 = *reinterpret_cast<const float4*>(xr + 8 * lane + 4);
        const float4 t2 = *reinterpret_cast<const float4*>(xr + 512 + 8 * lane);
        const float4 t3 = *reinterpret_cast<const float4*>(xr + 512 + 8 * lane + 4);
        x[0]=t0.x; x[1]=t0.y; x[2]=t0.z; x[3]=t0.w;
        x[4]=t1.x; x[5]=t1.y; x[6]=t1.z; x[7]=t1.w;
        x[8]=t2.x; x[9]=t2.y; x[10]=t2.z; x[11]=t2.w;
        x[12]=t3.x; x[13]=t3.y; x[14]=t3.z; x[15]=t3.w;
      }
      float q[16];
#pragma unroll
      for (int e = 0; e < 16; ++e)
        q[e] = expf((u2 - (Li - (x[e] - mi)) + v2f[e]) / EPSF) * 16384.0f;
      float* orow = Qf + (size_t)i * KC;
      *reinterpret_cast<float4*>(orow + 8 * lane)           = make_float4(q[0], q[1], q[2], q[3]);
      *reinterpret_cast<float4*>(orow + 8 * lane + 4)       = make_float4(q[4], q[5], q[6], q[7]);
      *reinterpret_cast<float4*>(orow + 512 + 8 * lane)     = make_float4(q[8], q[9], q[10], q[11]);
      *reinterpret_cast<float4*>(orow + 512 + 8 * lane + 4) = make_float4(q[12], q[13], q[14], q[15]);
    }
  }
}

extern "C" void kernel_launch(void* const* d_in, const int* in_sizes, int n_in,
                              void* d_out, int out_size, void* d_ws, size_t ws_size,
                              hipStream_t stream)
{
  (void)in_sizes; (void)n_in; (void)out_size; (void)ws_size;
  const float* X = (const float*)d_in[0];
  float* Qf = (float*)d_out;
  hipMemsetAsync(d_ws, 0, 16384, stream);   // arr + rel64 (tagged-b uses equality polls)
  void* args[3] = { (void*)&X, (void*)&Qf, (void*)&d_ws };
  hipLaunchCooperativeKernel((const void*)sk_coop, dim3(NBLK), dim3(NTHR),
                             args, 0, stream);
}